// Round 4
// baseline (264.669 us; speedup 1.0000x reference)
//
#include <hip/hip_runtime.h>
#include <stdint.h>

// DkNetCL: 4x [conv3x3(pad1) + SRePro(global-norm rescale)] + FC(32768->10).
// Key trick: SRePro scales the WHOLE sample by a scalar and conv is linear ->
// run convs on unscaled activations (bf16, NHWC), accumulate per-sample
// ||u_i||^2, fold the scalar chain into the FC epilogue.
// Conv = implicit GEMM via mfma_f32_16x16x32_bf16: M=Cout(32), K=Cin(32) per
// tap, N=pixels. Layer 0 zero-pads Cin 3->32 (same kernel for all layers).
// Conv runs IN-PLACE: whole sample is staged to LDS before any global write.

typedef __bf16 bf16x8 __attribute__((ext_vector_type(8)));
typedef float f32x4 __attribute__((ext_vector_type(4)));
typedef unsigned short u16;
typedef unsigned int u32;

__device__ __forceinline__ u16 f2bf(float f) {          // fp32 -> bf16 RNE
    union { float f; u32 i; } v; v.f = f;
    u32 r = v.i + 0x7FFFu + ((v.i >> 16) & 1u);
    return (u16)(r >> 16);
}
__device__ __forceinline__ float bf2f(u16 u) {          // bf16 -> fp32 exact
    union { u32 i; float f; } v; v.i = ((u32)u) << 16;
    return v.f;
}
union frag_cast { uint4 u; bf16x8 f; };

// ---------------- weight prep: OIHW fp32 -> MFMA A-frag bf16 ----------------
// layout: [layer][tap=dy*3+dx][mhalf][lane][8 cin]  (16B per (frag,lane))
__global__ void prep_weights_k(const float* __restrict__ w0, const float* __restrict__ w1,
                               const float* __restrict__ w2, const float* __restrict__ w3,
                               u16* __restrict__ wfrag)
{
    int idx = blockIdx.x * 256 + threadIdx.x;           // 4*9*2*64 = 4608
    if (idx >= 4 * 9 * 2 * 64) return;
    int lane  = idx & 63;
    int mh    = (idx >> 6) & 1;
    int tap   = (idx >> 7) % 9;
    int layer = (idx >> 7) / 9;
    const float* w = layer == 0 ? w0 : layer == 1 ? w1 : layer == 2 ? w2 : w3;
    int cin_act = (layer == 0) ? 3 : 32;
    int cout = mh * 16 + (lane & 15);
    int cin0 = (lane >> 4) * 8;
    int dy = tap / 3, dx = tap % 3;
    u16 v[8];
    for (int j = 0; j < 8; j++) {
        int cin = cin0 + j;
        float f = (cin < cin_act) ? w[((cout * cin_act + cin) * 3 + dy) * 3 + dx] : 0.f;
        v[j] = f2bf(f);
    }
    uint4 pack;
    pack.x = (u32)v[0] | ((u32)v[1] << 16);
    pack.y = (u32)v[2] | ((u32)v[3] << 16);
    pack.z = (u32)v[4] | ((u32)v[5] << 16);
    pack.w = (u32)v[6] | ((u32)v[7] << 16);
    reinterpret_cast<uint4*>(wfrag)[idx] = pack;
}

// ------------- fc weight transpose: NCHW-k order -> NHWC-k order ------------
__global__ void prep_fcwT_k(const float* __restrict__ fcw, float* __restrict__ fwT)
{
    int i = blockIdx.x * 256 + threadIdx.x;             // 10*32768
    if (i >= 327680) return;
    int j = i >> 15, r = i & 32767;
    int p = r >> 5, c = r & 31;
    fwT[i] = fcw[(j << 15) + (c << 10) + p];
}

// ---------- input convert: fp32 NCHW [B,3,32,32] -> bf16 NHWC 32ch ----------
__global__ void cvt_input_k(const float* __restrict__ x, u16* __restrict__ u0)
{
    int pix = blockIdx.x * 256 + threadIdx.x;           // 1024*1024 pixels
    int b = pix >> 10, p = pix & 1023;
    const float* xb = x + b * 3072 + p;
    u16 o[32];
    o[0] = f2bf(xb[0]); o[1] = f2bf(xb[1024]); o[2] = f2bf(xb[2048]);
#pragma unroll
    for (int c = 3; c < 32; c++) o[c] = 0;
    uint4* dst = reinterpret_cast<uint4*>(u0 + (size_t)pix * 32);
#pragma unroll
    for (int q = 0; q < 4; q++) {
        uint4 pk;
        pk.x = (u32)o[q*8+0] | ((u32)o[q*8+1] << 16);
        pk.y = (u32)o[q*8+2] | ((u32)o[q*8+3] << 16);
        pk.z = (u32)o[q*8+4] | ((u32)o[q*8+5] << 16);
        pk.w = (u32)o[q*8+6] | ((u32)o[q*8+7] << 16);
        dst[q] = pk;
    }
}

// ------------------------------- conv layer ---------------------------------
// block = 1 sample, 256 thr (4 waves). wave w: output rows 8w..8w+7.
// LDS: [32y][32x][40ch pad] bf16 = 81920B -> 2 blocks/CU, 2-way (free) banks.
// Per 2-row chunk: iterate 4 input rows, reuse B-frags for both out rows (dy
// via registers), 3 dx variants read from LDS. 72 MFMAs / chunk / wave.
// IN-PLACE: all global reads for sample b complete before the barrier; writes
// after. Blocks touch disjoint samples -> no cross-block hazard.
__global__ void __launch_bounds__(256, 2)
conv_layer_k(u16* __restrict__ u, const u16* __restrict__ wfl,
             float* __restrict__ normp)
{
    __shared__ u16 lds[32 * 32 * 40];
    const int b = blockIdx.x;
    const int tid = threadIdx.x;
    const int lane = tid & 63;
    const int wv = tid >> 6;

    // A-frags (weights): W[dy][dx][mh], 72 VGPRs
    bf16x8 W[3][3][2];
#pragma unroll
    for (int dy = 0; dy < 3; dy++)
#pragma unroll
        for (int dx = 0; dx < 3; dx++)
#pragma unroll
            for (int mh = 0; mh < 2; mh++) {
                frag_cast fc;
                fc.u = reinterpret_cast<const uint4*>(wfl)[((dy * 3 + dx) * 2 + mh) * 64 + lane];
                W[dy][dx][mh] = fc.f;
            }

    // stage sample into LDS (coalesced 16B quarters)
    u16* smp = u + (size_t)b * 32768;
#pragma unroll
    for (int it = 0; it < 16; it++) {
        int q = it * 256 + tid;                         // 4096 quarters
        int p = q >> 2;
        int c0 = (q & 3) * 8;
        uint4 v = *reinterpret_cast<const uint4*>(smp + p * 32 + c0);
        *reinterpret_cast<uint4*>(&lds[p * 40 + c0]) = v;
    }
    __syncthreads();

    const int px = lane & 15;
    const int kq = lane >> 4;
    float vnorm = 0.f;
    const int orow0 = wv * 8;

#pragma unroll 1
    for (int ch = 0; ch < 4; ch++) {
        const int oA = orow0 + ch * 2;                  // rows oA, oA+1
        f32x4 accA[2][2]; f32x4 accB[2][2];             // [mhalf][ntile]
#pragma unroll
        for (int mh = 0; mh < 2; mh++)
#pragma unroll
            for (int nt = 0; nt < 2; nt++) { accA[mh][nt] = (f32x4)0.f; accB[mh][nt] = (f32x4)0.f; }

#pragma unroll
        for (int k = 0; k < 4; k++) {
            int ri = oA - 1 + k;                        // input row
            if (ri >= 0 && ri < 32) {
                bf16x8 bfr[2][3];                       // [ntile][dx]
#pragma unroll
                for (int nt = 0; nt < 2; nt++)
#pragma unroll
                    for (int d = 0; d < 3; d++) {
                        int xx = nt * 16 + px + d - 1;
                        bool oob = ((unsigned)xx >= 32u);
                        int xc = oob ? (nt * 16 + px) : xx;
                        frag_cast fc;
                        fc.u = *reinterpret_cast<const uint4*>(&lds[(ri * 32 + xc) * 40 + kq * 8]);
                        if (oob) { fc.u.x = 0; fc.u.y = 0; fc.u.z = 0; fc.u.w = 0; }
                        bfr[nt][d] = fc.f;
                    }
                if (k <= 2) {                           // row oA, ky = k
#pragma unroll
                    for (int mh = 0; mh < 2; mh++)
#pragma unroll
                        for (int nt = 0; nt < 2; nt++)
#pragma unroll
                            for (int d = 0; d < 3; d++)
                                accA[mh][nt] = __builtin_amdgcn_mfma_f32_16x16x32_bf16(
                                    W[k][d][mh], bfr[nt][d], accA[mh][nt], 0, 0, 0);
                }
                if (k >= 1) {                           // row oA+1, ky = k-1
#pragma unroll
                    for (int mh = 0; mh < 2; mh++)
#pragma unroll
                        for (int nt = 0; nt < 2; nt++)
#pragma unroll
                            for (int d = 0; d < 3; d++)
                                accB[mh][nt] = __builtin_amdgcn_mfma_f32_16x16x32_bf16(
                                    W[k - 1][d][mh], bfr[nt][d], accB[mh][nt], 0, 0, 0);
                }
            }
        }
        // epilogue: D layout col(px)=lane&15, row(cout)=(lane>>4)*4+r
#pragma unroll
        for (int mh = 0; mh < 2; mh++)
#pragma unroll
            for (int nt = 0; nt < 2; nt++) {
                f32x4 a = accA[mh][nt];
                vnorm += a[0]*a[0] + a[1]*a[1] + a[2]*a[2] + a[3]*a[3];
                ushort4 h = make_ushort4(f2bf(a[0]), f2bf(a[1]), f2bf(a[2]), f2bf(a[3]));
                *reinterpret_cast<ushort4*>(smp + ((size_t)(oA * 32 + nt * 16 + px)) * 32 + mh * 16 + kq * 4) = h;
                f32x4 c = accB[mh][nt];
                vnorm += c[0]*c[0] + c[1]*c[1] + c[2]*c[2] + c[3]*c[3];
                ushort4 h2 = make_ushort4(f2bf(c[0]), f2bf(c[1]), f2bf(c[2]), f2bf(c[3]));
                *reinterpret_cast<ushort4*>(smp + ((size_t)((oA + 1) * 32 + nt * 16 + px)) * 32 + mh * 16 + kq * 4) = h2;
            }
    }

    // per-sample ||u||^2: wave reduce + one atomic per wave
#pragma unroll
    for (int off = 32; off; off >>= 1) vnorm += __shfl_xor(vnorm, off);
    if (lane == 0) atomicAdd(&normp[b], vnorm);
}

// ----------------- scalar chain: c_i = c * 2/(2 + c^2 * n_i) ----------------
__global__ void scale_k(const float* __restrict__ norms, float* __restrict__ c4)
{
    int b = blockIdx.x * 256 + threadIdx.x;
    if (b >= 1024) return;
    float c = 1.f;
#pragma unroll
    for (int i = 0; i < 4; i++) {
        float n = norms[i * 1024 + b];
        c = c * (2.f / (2.f + c * c * n));
    }
    c4[b] = c;
}

// -------------------- FC: out[b][j] = c4[b]*<u4,wT_j> + bias ----------------
__global__ void __launch_bounds__(256)
fc_k(const u16* __restrict__ u4, const float* __restrict__ fwT,
     const float* __restrict__ fcb, const float* __restrict__ c4,
     float* __restrict__ out)
{
    int lane = threadIdx.x & 63;
    int wv = threadIdx.x >> 6;
    int b = blockIdx.x * 4 + wv;                        // wave = sample
    const u16* ub = u4 + (size_t)b * 32768;
    float acc[10] = {0,0,0,0,0,0,0,0,0,0};
    for (int it = 0; it < 64; it++) {
        int k0 = it * 512 + lane * 8;                   // NHWC-flat k
        uint4 uv = *reinterpret_cast<const uint4*>(ub + k0);
        float uf[8];
        uf[0] = bf2f((u16)(uv.x & 0xFFFF)); uf[1] = bf2f((u16)(uv.x >> 16));
        uf[2] = bf2f((u16)(uv.y & 0xFFFF)); uf[3] = bf2f((u16)(uv.y >> 16));
        uf[4] = bf2f((u16)(uv.z & 0xFFFF)); uf[5] = bf2f((u16)(uv.z >> 16));
        uf[6] = bf2f((u16)(uv.w & 0xFFFF)); uf[7] = bf2f((u16)(uv.w >> 16));
#pragma unroll
        for (int j = 0; j < 10; j++) {
            const float4* wp = reinterpret_cast<const float4*>(fwT + j * 32768 + k0);
            float4 wa = wp[0], wb = wp[1];
            acc[j] += uf[0]*wa.x + uf[1]*wa.y + uf[2]*wa.z + uf[3]*wa.w
                    + uf[4]*wb.x + uf[5]*wb.y + uf[6]*wb.z + uf[7]*wb.w;
        }
    }
#pragma unroll
    for (int j = 0; j < 10; j++) {
#pragma unroll
        for (int off = 32; off; off >>= 1) acc[j] += __shfl_xor(acc[j], off);
    }
    if (lane == 0) {
        float c = c4[b];
#pragma unroll
        for (int j = 0; j < 10; j++) out[b * 10 + j] = c * acc[j] + fcb[j];
    }
}

// ------------------------------- launcher -----------------------------------
extern "C" void kernel_launch(void* const* d_in, const int* in_sizes, int n_in,
                              void* d_out, int out_size, void* d_ws, size_t ws_size,
                              hipStream_t stream)
{
    const float* x   = (const float*)d_in[0];
    const float* cw0 = (const float*)d_in[1];
    const float* cw1 = (const float*)d_in[2];
    const float* cw2 = (const float*)d_in[3];
    const float* cw3 = (const float*)d_in[4];
    const float* fcw = (const float*)d_in[5];
    const float* fcb = (const float*)d_in[6];
    float* out = (float*)d_out;
    char* ws = (char*)d_ws;

    // ws layout (~65.5 MB): single in-place activation buffer + prep areas
    const size_t USZ = (size_t)1024 * 32768 * 2;        // 64 MB activation buf
    u16* uA      = (u16*)ws;
    u16* wfrag   = (u16*)(ws + USZ);                    // 73728 B (pad 81920)
    float* fwT   = (float*)(ws + USZ + 81920);          // 1310720 B
    float* norms = (float*)(ws + USZ + 81920 + 1310720);// 16 KB
    float* c4    = norms + 4096;

    hipMemsetAsync(norms, 0, 4096 * sizeof(float), stream);
    prep_weights_k<<<18, 256, 0, stream>>>(cw0, cw1, cw2, cw3, wfrag);
    prep_fcwT_k<<<1280, 256, 0, stream>>>(fcw, fwT);
    cvt_input_k<<<4096, 256, 0, stream>>>(x, uA);

    const int LW = 9 * 2 * 64 * 8;                      // 9216 u16 per layer
    conv_layer_k<<<1024, 256, 0, stream>>>(uA, wfrag,          norms);
    conv_layer_k<<<1024, 256, 0, stream>>>(uA, wfrag + LW,     norms + 1024);
    conv_layer_k<<<1024, 256, 0, stream>>>(uA, wfrag + 2 * LW, norms + 2048);
    conv_layer_k<<<1024, 256, 0, stream>>>(uA, wfrag + 3 * LW, norms + 3072);

    scale_k<<<4, 256, 0, stream>>>(norms, c4);
    fc_k<<<256, 256, 0, stream>>>(uA, fwT, fcb, c4, out);
}

// Round 6
// 222.014 us; speedup vs baseline: 1.1921x; 1.1921x over previous
//
#include <hip/hip_runtime.h>
#include <stdint.h>

// DkNetCL fused: one megakernel does cvt + 4x conv3x3 (LDS-resident ping-pong,
// deferred SRePro scales -> c4[b]), then MFMA FC (double-bf16 weights, k-split
// + atomic partials) + finalize. Conv = implicit GEMM mfma_f32_16x16x32_bf16,
// M=Cout(32), K=Cin(32) per tap, N=pixels. Verified frag layouts from round 4.

typedef __bf16 bf16x8 __attribute__((ext_vector_type(8)));
typedef float f32x4 __attribute__((ext_vector_type(4)));
typedef unsigned short u16;
typedef unsigned int u32;

__device__ __forceinline__ u16 f2bf(float f) {          // fp32 -> bf16 RNE
    union { float f; u32 i; } v; v.f = f;
    u32 r = v.i + 0x7FFFu + ((v.i >> 16) & 1u);
    return (u16)(r >> 16);
}
__device__ __forceinline__ float bf2f(u16 u) {
    union { u32 i; float f; } v; v.i = ((u32)u) << 16;
    return v.f;
}
union frag_cast { uint4 u; bf16x8 f; };

// ---------------- conv weight prep: OIHW fp32 -> MFMA A-frag bf16 -----------
// layout: [layer][tap=dy*3+dx][mhalf][lane][8 cin]  (16B per (frag,lane))
__global__ void prep_weights_k(const float* __restrict__ w0, const float* __restrict__ w1,
                               const float* __restrict__ w2, const float* __restrict__ w3,
                               u16* __restrict__ wfrag)
{
    int idx = blockIdx.x * 256 + threadIdx.x;           // 4*9*2*64 = 4608
    if (idx >= 4 * 9 * 2 * 64) return;
    int lane  = idx & 63;
    int mh    = (idx >> 6) & 1;
    int tap   = (idx >> 7) % 9;
    int layer = (idx >> 7) / 9;
    const float* w = layer == 0 ? w0 : layer == 1 ? w1 : layer == 2 ? w2 : w3;
    int cin_act = (layer == 0) ? 3 : 32;
    int cout = mh * 16 + (lane & 15);
    int cin0 = (lane >> 4) * 8;
    int dy = tap / 3, dx = tap % 3;
    u16 v[8];
    for (int j = 0; j < 8; j++) {
        int cin = cin0 + j;
        float f = (cin < cin_act) ? w[((cout * cin_act + cin) * 3 + dy) * 3 + dx] : 0.f;
        v[j] = f2bf(f);
    }
    uint4 pack;
    pack.x = (u32)v[0] | ((u32)v[1] << 16);
    pack.y = (u32)v[2] | ((u32)v[3] << 16);
    pack.z = (u32)v[4] | ((u32)v[5] << 16);
    pack.w = (u32)v[6] | ((u32)v[7] << 16);
    reinterpret_cast<uint4*>(wfrag)[idx] = pack;
}

// ------- FC weight prep: fp32 [10][32768 nchw] -> double-bf16 A-frags -------
// plane 0 = hi, plane 1 = lo (w - hi); each: [1024 step][64 lane][8 k] bf16.
// A-frag: row j = lane&15 (j>=10 zero), k = (lane>>4)*8 + e, k in NHWC order.
__global__ void prep_wfc_k(const float* __restrict__ fcw, u16* __restrict__ wfc)
{
    int idx = blockIdx.x * 256 + threadIdx.x;           // 1024*64 = 65536
    int lane = idx & 63, step = idx >> 6;
    int j = lane & 15, kq = lane >> 4;
    u16 hi[8], lo[8];
#pragma unroll
    for (int e = 0; e < 8; e++) {
        int k = step * 32 + kq * 8 + e;                 // NHWC k
        int c = k & 31, p = k >> 5;
        float f = (j < 10) ? fcw[j * 32768 + c * 1024 + p] : 0.f;
        u16 h = f2bf(f);
        hi[e] = h;
        lo[e] = f2bf(f - bf2f(h));
    }
    uint4 ph, pl;
    ph.x = (u32)hi[0] | ((u32)hi[1] << 16); ph.y = (u32)hi[2] | ((u32)hi[3] << 16);
    ph.z = (u32)hi[4] | ((u32)hi[5] << 16); ph.w = (u32)hi[6] | ((u32)hi[7] << 16);
    pl.x = (u32)lo[0] | ((u32)lo[1] << 16); pl.y = (u32)lo[2] | ((u32)lo[3] << 16);
    pl.z = (u32)lo[4] | ((u32)lo[5] << 16); pl.w = (u32)lo[6] | ((u32)lo[7] << 16);
    reinterpret_cast<uint4*>(wfc)[idx] = ph;
    reinterpret_cast<uint4*>(wfc)[65536 + idx] = pl;
}

// ------------------------------ megakernel ----------------------------------
// block = 1 sample, 256 thr (4 waves). LDS ping-pong 2 x [1024 pix][32 ch] bf16
// (64KB each). cvt -> buf0; layer l: buf(l&1) -> buf(1-(l&1)); final in buf0.
// Per-layer barrier only. Norm chain reduced in-block -> c4[b].
__global__ void __launch_bounds__(256, 1)
net_k(const float* __restrict__ x, const u16* __restrict__ wfrag,
      u16* __restrict__ u4, float* __restrict__ c4)
{
    __shared__ u16 lds[2][32768];
    __shared__ float red[4][4];                         // [wave][layer]
    const int b = blockIdx.x;
    const int tid = threadIdx.x;
    const int lane = tid & 63;
    const int wv = tid >> 6;
    const int px = lane & 15;
    const int kq = lane >> 4;
    float vn[4] = {0.f, 0.f, 0.f, 0.f};

    // ---- cvt: fp32 NCHW -> bf16 NHWC(32ch, ch3..31 = 0) into lds[0] ----
    const float* xb = x + (size_t)b * 3072;
#pragma unroll
    for (int it = 0; it < 16; it++) {
        int Q = it * 256 + tid;                         // quad index 0..4095
        int pix = Q >> 2, q = Q & 3;
        uint4 val = make_uint4(0, 0, 0, 0);
        if (q == 0) {
            float f0 = xb[pix], f1 = xb[1024 + pix], f2 = xb[2048 + pix];
            val.x = (u32)f2bf(f0) | ((u32)f2bf(f1) << 16);
            val.y = (u32)f2bf(f2);                      // ch3 = 0
        }
        *reinterpret_cast<uint4*>(&lds[0][Q * 8]) = val;
    }

    const int orow0 = wv * 8;
#pragma unroll 1
    for (int l = 0; l < 4; l++) {
        // load this layer's A-frags (global, independent of LDS)
        bf16x8 W[3][3][2];
        const uint4* wl = reinterpret_cast<const uint4*>(wfrag + l * 9216);
#pragma unroll
        for (int dy = 0; dy < 3; dy++)
#pragma unroll
            for (int dx = 0; dx < 3; dx++)
#pragma unroll
                for (int mh = 0; mh < 2; mh++) {
                    frag_cast fc;
                    fc.u = wl[((dy * 3 + dx) * 2 + mh) * 64 + lane];
                    W[dy][dx][mh] = fc.f;
                }
        const u16* src = lds[l & 1];
        u16* dst = lds[(l & 1) ^ 1];
        __syncthreads();                                // prev writes visible

#pragma unroll 1
        for (int ch = 0; ch < 4; ch++) {
            const int oA = orow0 + ch * 2;              // rows oA, oA+1
            f32x4 accA[2][2]; f32x4 accB[2][2];         // [mhalf][ntile]
#pragma unroll
            for (int mh = 0; mh < 2; mh++)
#pragma unroll
                for (int nt = 0; nt < 2; nt++) { accA[mh][nt] = (f32x4)0.f; accB[mh][nt] = (f32x4)0.f; }

#pragma unroll
            for (int k = 0; k < 4; k++) {
                int ri = oA - 1 + k;                    // input row
                if (ri >= 0 && ri < 32) {
                    bf16x8 bfr[2][3];                   // [ntile][dx]
#pragma unroll
                    for (int nt = 0; nt < 2; nt++)
#pragma unroll
                        for (int d = 0; d < 3; d++) {
                            int xx = nt * 16 + px + d - 1;
                            bool oob = ((unsigned)xx >= 32u);
                            int xc = oob ? (nt * 16 + px) : xx;
                            frag_cast fc;
                            fc.u = *reinterpret_cast<const uint4*>(&src[(ri * 32 + xc) * 32 + kq * 8]);
                            if (oob) { fc.u.x = 0; fc.u.y = 0; fc.u.z = 0; fc.u.w = 0; }
                            bfr[nt][d] = fc.f;
                        }
                    if (k <= 2) {
#pragma unroll
                        for (int mh = 0; mh < 2; mh++)
#pragma unroll
                            for (int nt = 0; nt < 2; nt++)
#pragma unroll
                                for (int d = 0; d < 3; d++)
                                    accA[mh][nt] = __builtin_amdgcn_mfma_f32_16x16x32_bf16(
                                        W[k][d][mh], bfr[nt][d], accA[mh][nt], 0, 0, 0);
                    }
                    if (k >= 1) {
#pragma unroll
                        for (int mh = 0; mh < 2; mh++)
#pragma unroll
                            for (int nt = 0; nt < 2; nt++)
#pragma unroll
                                for (int d = 0; d < 3; d++)
                                    accB[mh][nt] = __builtin_amdgcn_mfma_f32_16x16x32_bf16(
                                        W[k - 1][d][mh], bfr[nt][d], accB[mh][nt], 0, 0, 0);
                    }
                }
            }
            // epilogue: D col=lane&15(pixel x), row(ch)=(lane>>4)*4+r
#pragma unroll
            for (int mh = 0; mh < 2; mh++)
#pragma unroll
                for (int nt = 0; nt < 2; nt++) {
                    f32x4 a = accA[mh][nt];
                    vn[l] += a[0]*a[0] + a[1]*a[1] + a[2]*a[2] + a[3]*a[3];
                    ushort4 h = make_ushort4(f2bf(a[0]), f2bf(a[1]), f2bf(a[2]), f2bf(a[3]));
                    *reinterpret_cast<ushort4*>(&dst[((oA * 32 + nt * 16 + px)) * 32 + mh * 16 + kq * 4]) = h;
                    f32x4 c = accB[mh][nt];
                    vn[l] += c[0]*c[0] + c[1]*c[1] + c[2]*c[2] + c[3]*c[3];
                    ushort4 h2 = make_ushort4(f2bf(c[0]), f2bf(c[1]), f2bf(c[2]), f2bf(c[3]));
                    *reinterpret_cast<ushort4*>(&dst[(((oA + 1) * 32 + nt * 16 + px)) * 32 + mh * 16 + kq * 4]) = h2;
                }
        }
    }

    // ---- norm chain -> c4[b] ----
#pragma unroll
    for (int l = 0; l < 4; l++)
#pragma unroll
        for (int off = 32; off; off >>= 1) vn[l] += __shfl_xor(vn[l], off);
    if (lane == 0) {
#pragma unroll
        for (int l = 0; l < 4; l++) red[wv][l] = vn[l];
    }
    __syncthreads();                                    // red + final lds[0] visible
    float c = 1.f;
#pragma unroll
    for (int l = 0; l < 4; l++) {
        float n = red[0][l] + red[1][l] + red[2][l] + red[3][l];
        c = c * (2.f / (2.f + c * c * n));
    }
    if (tid == 0) c4[b] = c;

    // ---- writeback final activation (buf0, unscaled) ----
    u16* ub = u4 + (size_t)b * 32768;
#pragma unroll
    for (int it = 0; it < 16; it++) {
        int Q = it * 256 + tid;
        *reinterpret_cast<uint4*>(ub + Q * 8) =
            *reinterpret_cast<const uint4*>(&lds[0][Q * 8]);
    }
}

// --------------- FC: MFMA, M=16(j), N=16 samples, 32-way k-split ------------
// wave task = (k-chunk, sample-tile). acc += Whi*B + Wlo*B. Partials -> atomic.
__global__ void __launch_bounds__(256)
fc_mfma_k(const u16* __restrict__ u4, const u16* __restrict__ wfc,
          float* __restrict__ tmp)
{
    const int lane = threadIdx.x & 63;
    const int wv = threadIdx.x >> 6;
    const int wid = blockIdx.x * 4 + wv;                // 0..2047
    const int kc = wid & 31;                            // k-chunk (1024 elems)
    const int st = wid >> 5;                            // sample tile (16)
    const int px = lane & 15, kq = lane >> 4;
    const uint4* Ah = reinterpret_cast<const uint4*>(wfc) + kc * 32 * 64 + lane;
    const uint4* Al = Ah + 65536;
    const u16* B = u4 + (size_t)(st * 16 + px) * 32768 + kc * 1024 + kq * 8;
    f32x4 acc = (f32x4)0.f;
#pragma unroll
    for (int s = 0; s < 32; s++) {
        frag_cast a, al, bb;
        a.u  = Ah[s * 64];
        al.u = Al[s * 64];
        bb.u = *reinterpret_cast<const uint4*>(B + s * 32);
        acc = __builtin_amdgcn_mfma_f32_16x16x32_bf16(a.f,  bb.f, acc, 0, 0, 0);
        acc = __builtin_amdgcn_mfma_f32_16x16x32_bf16(al.f, bb.f, acc, 0, 0, 0);
    }
    int sample = st * 16 + px;                          // D col = lane&15
#pragma unroll
    for (int r = 0; r < 4; r++) {
        int j = kq * 4 + r;                             // D row
        if (j < 10) atomicAdd(&tmp[sample * 10 + j], acc[r]);
    }
}

// ------------------- finalize: out = c4[b]*tmp + bias -----------------------
__global__ void finalize_k(const float* __restrict__ tmp, const float* __restrict__ c4,
                           const float* __restrict__ fcb, float* __restrict__ out)
{
    int i = blockIdx.x * 256 + threadIdx.x;
    if (i >= 10240) return;
    int b = i / 10, j = i - b * 10;
    out[i] = c4[b] * tmp[i] + fcb[j];
}

// ------------------------------- launcher -----------------------------------
extern "C" void kernel_launch(void* const* d_in, const int* in_sizes, int n_in,
                              void* d_out, int out_size, void* d_ws, size_t ws_size,
                              hipStream_t stream)
{
    const float* x   = (const float*)d_in[0];
    const float* cw0 = (const float*)d_in[1];
    const float* cw1 = (const float*)d_in[2];
    const float* cw2 = (const float*)d_in[3];
    const float* cw3 = (const float*)d_in[4];
    const float* fcw = (const float*)d_in[5];
    const float* fcb = (const float*)d_in[6];
    float* out = (float*)d_out;
    char* ws = (char*)d_ws;

    // ws layout (~66.2 MB)
    const size_t USZ = (size_t)1024 * 32768 * 2;        // 64 MB activations
    u16* uA    = (u16*)ws;
    u16* wfrag = (u16*)(ws + USZ);                      // 73728 B (pad 81920)
    u16* wfc   = (u16*)(ws + USZ + 81920);              // 2 MB (hi+lo)
    float* tmp = (float*)(ws + USZ + 81920 + 2097152);  // 40960 B
    float* c4  = tmp + 10240;                           // 4096 B

    hipMemsetAsync(tmp, 0, 10240 * sizeof(float), stream);
    prep_weights_k<<<18, 256, 0, stream>>>(cw0, cw1, cw2, cw3, wfrag);
    prep_wfc_k<<<256, 256, 0, stream>>>(fcw, wfc);
    net_k<<<1024, 256, 0, stream>>>(x, wfrag, uA, c4);
    fc_mfma_k<<<512, 256, 0, stream>>>(uA, wfc, tmp);
    finalize_k<<<40, 256, 0, stream>>>(tmp, c4, fcb, out);
}

// Round 10
// 193.303 us; speedup vs baseline: 1.3692x; 1.1485x over previous
//
#include <hip/hip_runtime.h>
#include <stdint.h>

// DkNetCL fused: megakernel (cvt + 4x conv3x3, LDS ping-pong, deferred SRePro
// -> c4[b]) + MFMA FC (double-bf16 weights, k-split atomics) + finalize.
// Conv = implicit GEMM mfma_f32_16x16x32_bf16, M=Cout(32), K=Cin(32)/tap.
// R6 fix: LDS chunk XOR-swizzle off(p,c)=p*32+((c^((p>>1)&3))*8) kills the
// 4-way bank conflict (2.08e7 cy) of the 64B/pixel layout; 8 waves (512 thr).

typedef __bf16 bf16x8 __attribute__((ext_vector_type(8)));
typedef float f32x4 __attribute__((ext_vector_type(4)));
typedef unsigned short u16;
typedef unsigned int u32;

__device__ __forceinline__ u16 f2bf(float f) {          // fp32 -> bf16 RNE
    union { float f; u32 i; } v; v.f = f;
    u32 r = v.i + 0x7FFFu + ((v.i >> 16) & 1u);
    return (u16)(r >> 16);
}
__device__ __forceinline__ float bf2f(u16 u) {
    union { u32 i; float f; } v; v.i = ((u32)u) << 16;
    return v.f;
}
union frag_cast { uint4 u; bf16x8 f; };

// swizzled u16 offset of 16B-chunk c (0..3) of pixel p (0..1023)
__device__ __forceinline__ int swz(int p, int c) {
    return p * 32 + ((c ^ ((p >> 1) & 3)) * 8);
}

// ---------------- conv weight prep: OIHW fp32 -> MFMA A-frag bf16 -----------
__global__ void prep_weights_k(const float* __restrict__ w0, const float* __restrict__ w1,
                               const float* __restrict__ w2, const float* __restrict__ w3,
                               u16* __restrict__ wfrag)
{
    int idx = blockIdx.x * 256 + threadIdx.x;           // 4*9*2*64 = 4608
    if (idx >= 4 * 9 * 2 * 64) return;
    int lane  = idx & 63;
    int mh    = (idx >> 6) & 1;
    int tap   = (idx >> 7) % 9;
    int layer = (idx >> 7) / 9;
    const float* w = layer == 0 ? w0 : layer == 1 ? w1 : layer == 2 ? w2 : w3;
    int cin_act = (layer == 0) ? 3 : 32;
    int cout = mh * 16 + (lane & 15);
    int cin0 = (lane >> 4) * 8;
    int dy = tap / 3, dx = tap % 3;
    u16 v[8];
    for (int j = 0; j < 8; j++) {
        int cin = cin0 + j;
        float f = (cin < cin_act) ? w[((cout * cin_act + cin) * 3 + dy) * 3 + dx] : 0.f;
        v[j] = f2bf(f);
    }
    uint4 pack;
    pack.x = (u32)v[0] | ((u32)v[1] << 16);
    pack.y = (u32)v[2] | ((u32)v[3] << 16);
    pack.z = (u32)v[4] | ((u32)v[5] << 16);
    pack.w = (u32)v[6] | ((u32)v[7] << 16);
    reinterpret_cast<uint4*>(wfrag)[idx] = pack;
}

// ------- FC weight prep: fp32 [10][32768 nchw] -> double-bf16 A-frags -------
__global__ void prep_wfc_k(const float* __restrict__ fcw, u16* __restrict__ wfc)
{
    int idx = blockIdx.x * 256 + threadIdx.x;           // 1024*64 = 65536
    int lane = idx & 63, step = idx >> 6;
    int j = lane & 15, kq = lane >> 4;
    u16 hi[8], lo[8];
#pragma unroll
    for (int e = 0; e < 8; e++) {
        int k = step * 32 + kq * 8 + e;                 // NHWC k
        int c = k & 31, p = k >> 5;
        float f = (j < 10) ? fcw[j * 32768 + c * 1024 + p] : 0.f;
        u16 h = f2bf(f);
        hi[e] = h;
        lo[e] = f2bf(f - bf2f(h));
    }
    uint4 ph, pl;
    ph.x = (u32)hi[0] | ((u32)hi[1] << 16); ph.y = (u32)hi[2] | ((u32)hi[3] << 16);
    ph.z = (u32)hi[4] | ((u32)hi[5] << 16); ph.w = (u32)hi[6] | ((u32)hi[7] << 16);
    pl.x = (u32)lo[0] | ((u32)lo[1] << 16); pl.y = (u32)lo[2] | ((u32)lo[3] << 16);
    pl.z = (u32)lo[4] | ((u32)lo[5] << 16); pl.w = (u32)lo[6] | ((u32)lo[7] << 16);
    reinterpret_cast<uint4*>(wfc)[idx] = ph;
    reinterpret_cast<uint4*>(wfc)[65536 + idx] = pl;
}

// ------------------------------ megakernel ----------------------------------
// block = 1 sample, 512 thr (8 waves). LDS ping-pong 2 x 1024pix x 32ch bf16,
// chunk-swizzled. wave w: output rows 4w..4w+3 (2 chunks of 2 rows).
__global__ void __launch_bounds__(512, 1)
net_k(const float* __restrict__ x, const u16* __restrict__ wfrag,
      u16* __restrict__ u4, float* __restrict__ c4)
{
    __shared__ u16 lds[2][32768];
    __shared__ float red[8][4];                         // [wave][layer]
    const int b = blockIdx.x;
    const int tid = threadIdx.x;
    const int lane = tid & 63;
    const int wv = tid >> 6;
    const int px = lane & 15;
    const int kq = lane >> 4;
    float vn[4] = {0.f, 0.f, 0.f, 0.f};

    // ---- cvt: fp32 NCHW -> bf16 NHWC(32ch, ch3..31=0), swizzled lds[0] ----
    const float* xb = x + (size_t)b * 3072;
#pragma unroll
    for (int it = 0; it < 8; it++) {
        int pix = it * 128 + wv * 16 + px;              // wave covers 16 pix
        int c = kq;                                     // chunk = lane>>4
        uint4 val = make_uint4(0, 0, 0, 0);
        if (c == 0) {
            float f0 = xb[pix], f1 = xb[1024 + pix], f2 = xb[2048 + pix];
            val.x = (u32)f2bf(f0) | ((u32)f2bf(f1) << 16);
            val.y = (u32)f2bf(f2);
        }
        *reinterpret_cast<uint4*>(&lds[0][swz(pix, c)]) = val;
    }

    const int orow0 = wv * 4;
#pragma unroll 1
    for (int l = 0; l < 4; l++) {
        bf16x8 W[3][3][2];
        const uint4* wl = reinterpret_cast<const uint4*>(wfrag + l * 9216);
#pragma unroll
        for (int dy = 0; dy < 3; dy++)
#pragma unroll
            for (int dx = 0; dx < 3; dx++)
#pragma unroll
                for (int mh = 0; mh < 2; mh++) {
                    frag_cast fc;
                    fc.u = wl[((dy * 3 + dx) * 2 + mh) * 64 + lane];
                    W[dy][dx][mh] = fc.f;
                }
        const u16* src = lds[l & 1];
        u16* dst = lds[(l & 1) ^ 1];
        __syncthreads();                                // prev writes visible

#pragma unroll 1
        for (int ch = 0; ch < 2; ch++) {
            const int oA = orow0 + ch * 2;              // rows oA, oA+1
            f32x4 accA[2][2]; f32x4 accB[2][2];         // [mhalf][ntile]
#pragma unroll
            for (int mh = 0; mh < 2; mh++)
#pragma unroll
                for (int nt = 0; nt < 2; nt++) { accA[mh][nt] = (f32x4)0.f; accB[mh][nt] = (f32x4)0.f; }

#pragma unroll
            for (int k = 0; k < 4; k++) {
                int ri = oA - 1 + k;                    // input row
                if (ri >= 0 && ri < 32) {
                    bf16x8 bfr[2][3];                   // [ntile][dx]
#pragma unroll
                    for (int nt = 0; nt < 2; nt++)
#pragma unroll
                        for (int d = 0; d < 3; d++) {
                            int xx = nt * 16 + px + d - 1;
                            bool oob = ((unsigned)xx >= 32u);
                            int xc = oob ? (nt * 16 + px) : xx;
                            frag_cast fc;
                            fc.u = *reinterpret_cast<const uint4*>(&src[swz(ri * 32 + xc, kq)]);
                            if (oob) { fc.u.x = 0; fc.u.y = 0; fc.u.z = 0; fc.u.w = 0; }
                            bfr[nt][d] = fc.f;
                        }
                    if (k <= 2) {
#pragma unroll
                        for (int mh = 0; mh < 2; mh++)
#pragma unroll
                            for (int nt = 0; nt < 2; nt++)
#pragma unroll
                                for (int d = 0; d < 3; d++)
                                    accA[mh][nt] = __builtin_amdgcn_mfma_f32_16x16x32_bf16(
                                        W[k][d][mh], bfr[nt][d], accA[mh][nt], 0, 0, 0);
                    }
                    if (k >= 1) {
#pragma unroll
                        for (int mh = 0; mh < 2; mh++)
#pragma unroll
                            for (int nt = 0; nt < 2; nt++)
#pragma unroll
                                for (int d = 0; d < 3; d++)
                                    accB[mh][nt] = __builtin_amdgcn_mfma_f32_16x16x32_bf16(
                                        W[k - 1][d][mh], bfr[nt][d], accB[mh][nt], 0, 0, 0);
                    }
                }
            }
            // epilogue: D col=lane&15(px), row(ch)=(lane>>4)*4+r
            // dst u16 off = P*32 + (chunk^((P>>1)&3))*8 + (kq&1)*4,
            //   chunk = mh*2 + (kq>>1)
#pragma unroll
            for (int mh = 0; mh < 2; mh++)
#pragma unroll
                for (int nt = 0; nt < 2; nt++) {
                    int cch = mh * 2 + (kq >> 1);
                    int sub = (kq & 1) * 4;
                    f32x4 a = accA[mh][nt];
                    vn[l] += a[0]*a[0] + a[1]*a[1] + a[2]*a[2] + a[3]*a[3];
                    ushort4 h = make_ushort4(f2bf(a[0]), f2bf(a[1]), f2bf(a[2]), f2bf(a[3]));
                    int P0 = oA * 32 + nt * 16 + px;
                    *reinterpret_cast<ushort4*>(&dst[swz(P0, cch) + sub]) = h;
                    f32x4 c = accB[mh][nt];
                    vn[l] += c[0]*c[0] + c[1]*c[1] + c[2]*c[2] + c[3]*c[3];
                    ushort4 h2 = make_ushort4(f2bf(c[0]), f2bf(c[1]), f2bf(c[2]), f2bf(c[3]));
                    int P1 = (oA + 1) * 32 + nt * 16 + px;
                    *reinterpret_cast<ushort4*>(&dst[swz(P1, cch) + sub]) = h2;
                }
        }
    }

    // ---- norm chain -> c4[b] ----
#pragma unroll
    for (int l = 0; l < 4; l++)
#pragma unroll
        for (int off = 32; off; off >>= 1) vn[l] += __shfl_xor(vn[l], off);
    if (lane == 0) {
#pragma unroll
        for (int l = 0; l < 4; l++) red[wv][l] = vn[l];
    }
    __syncthreads();                                    // red + final lds[0] visible
    float c = 1.f;
#pragma unroll
    for (int l = 0; l < 4; l++) {
        float n = 0.f;
#pragma unroll
        for (int w = 0; w < 8; w++) n += red[w][l];
        c = c * (2.f / (2.f + c * c * n));
    }
    if (tid == 0) c4[b] = c;

    // ---- writeback final activation (lds[0], unswizzle -> linear NHWC) ----
    u16* ub = u4 + (size_t)b * 32768;
#pragma unroll
    for (int it = 0; it < 8; it++) {
        int pix = it * 128 + wv * 16 + px;
        int cch = kq;
        *reinterpret_cast<uint4*>(ub + pix * 32 + cch * 8) =
            *reinterpret_cast<const uint4*>(&lds[0][swz(pix, cch)]);
    }
}

// --------------- FC: MFMA, M=16(j), N=16 samples, 32-way k-split ------------
__global__ void __launch_bounds__(256)
fc_mfma_k(const u16* __restrict__ u4, const u16* __restrict__ wfc,
          float* __restrict__ tmp)
{
    const int lane = threadIdx.x & 63;
    const int wv = threadIdx.x >> 6;
    const int wid = blockIdx.x * 4 + wv;                // 0..2047
    const int kc = wid & 31;                            // k-chunk (1024 elems)
    const int st = wid >> 5;                            // sample tile (16)
    const int px = lane & 15, kq = lane >> 4;
    const uint4* Ah = reinterpret_cast<const uint4*>(wfc) + kc * 32 * 64 + lane;
    const uint4* Al = Ah + 65536;
    const u16* B = u4 + (size_t)(st * 16 + px) * 32768 + kc * 1024 + kq * 8;
    f32x4 acc = (f32x4)0.f;
#pragma unroll
    for (int s = 0; s < 32; s++) {
        frag_cast a, al, bb;
        a.u  = Ah[s * 64];
        al.u = Al[s * 64];
        bb.u = *reinterpret_cast<const uint4*>(B + s * 32);
        acc = __builtin_amdgcn_mfma_f32_16x16x32_bf16(a.f,  bb.f, acc, 0, 0, 0);
        acc = __builtin_amdgcn_mfma_f32_16x16x32_bf16(al.f, bb.f, acc, 0, 0, 0);
    }
    int sample = st * 16 + px;                          // D col = lane&15
#pragma unroll
    for (int r = 0; r < 4; r++) {
        int j = kq * 4 + r;                             // D row
        if (j < 10) atomicAdd(&tmp[sample * 10 + j], acc[r]);
    }
}

// ------------------- finalize: out = c4[b]*tmp + bias -----------------------
__global__ void finalize_k(const float* __restrict__ tmp, const float* __restrict__ c4,
                           const float* __restrict__ fcb, float* __restrict__ out)
{
    int i = blockIdx.x * 256 + threadIdx.x;
    if (i >= 10240) return;
    int b = i / 10, j = i - b * 10;
    out[i] = c4[b] * tmp[i] + fcb[j];
}

// ------------------------------- launcher -----------------------------------
extern "C" void kernel_launch(void* const* d_in, const int* in_sizes, int n_in,
                              void* d_out, int out_size, void* d_ws, size_t ws_size,
                              hipStream_t stream)
{
    const float* x   = (const float*)d_in[0];
    const float* cw0 = (const float*)d_in[1];
    const float* cw1 = (const float*)d_in[2];
    const float* cw2 = (const float*)d_in[3];
    const float* cw3 = (const float*)d_in[4];
    const float* fcw = (const float*)d_in[5];
    const float* fcb = (const float*)d_in[6];
    float* out = (float*)d_out;
    char* ws = (char*)d_ws;

    // ws layout (~66.2 MB)
    const size_t USZ = (size_t)1024 * 32768 * 2;        // 64 MB activations
    u16* uA    = (u16*)ws;
    u16* wfrag = (u16*)(ws + USZ);                      // 73728 B (pad 81920)
    u16* wfc   = (u16*)(ws + USZ + 81920);              // 2 MB (hi+lo)
    float* tmp = (float*)(ws + USZ + 81920 + 2097152);  // 40960 B
    float* c4  = tmp + 10240;                           // 4096 B

    hipMemsetAsync(tmp, 0, 10240 * sizeof(float), stream);
    prep_weights_k<<<18, 256, 0, stream>>>(cw0, cw1, cw2, cw3, wfrag);
    prep_wfc_k<<<256, 256, 0, stream>>>(fcw, wfc);
    net_k<<<1024, 512, 0, stream>>>(x, wfrag, uA, c4);
    fc_mfma_k<<<512, 256, 0, stream>>>(uA, wfc, tmp);
    finalize_k<<<40, 256, 0, stream>>>(tmp, c4, fcb, out);
}

// Round 12
// 188.005 us; speedup vs baseline: 1.4078x; 1.0282x over previous
//
#include <hip/hip_runtime.h>
#include <stdint.h>

// DkNetCL fused: megakernel (cvt + 4x conv3x3, LDS ping-pong, deferred SRePro
// -> c4[b]) + MFMA FC (double-bf16 weights, wave-private LDS-staged B) +
// finalize. Conv = implicit GEMM mfma_f32_16x16x32_bf16, M=Cout, K=Cin/tap.
// R10: swizzle cut bank conflicts 10x; now VALU-bound (39%). R11: native bf16
// casts, pointer-select OOB, ch-unroll (CSE of shared-row reads), fc staged
// through LDS for coalesced B (64B/4-lane groups), T14 async split, 0 barriers.

typedef __bf16 bf16x8 __attribute__((ext_vector_type(8)));
typedef float f32x4 __attribute__((ext_vector_type(4)));
typedef unsigned short u16;
typedef unsigned int u32;

__device__ __forceinline__ u16 f2bf(float f) {          // fp32 -> bf16 RNE (prep)
    union { float f; u32 i; } v; v.f = f;
    u32 r = v.i + 0x7FFFu + ((v.i >> 16) & 1u);
    return (u16)(r >> 16);
}
__device__ __forceinline__ float bf2f(u16 u) {
    union { u32 i; float f; } v; v.i = ((u32)u) << 16;
    return v.f;
}
__device__ __forceinline__ u16 bfc(float f) {           // HW cvt (fast path)
    union { __bf16 h; u16 u; } x; x.h = (__bf16)f; return x.u;
}
union frag_cast { uint4 u; bf16x8 f; };

// swizzled u16 offset of 16B-chunk c (0..3) of pixel p (0..1023)
__device__ __forceinline__ int swz(int p, int c) {
    return p * 32 + ((c ^ ((p >> 1) & 3)) * 8);
}

// ---------------- conv weight prep: OIHW fp32 -> MFMA A-frag bf16 -----------
__global__ void prep_weights_k(const float* __restrict__ w0, const float* __restrict__ w1,
                               const float* __restrict__ w2, const float* __restrict__ w3,
                               u16* __restrict__ wfrag)
{
    int idx = blockIdx.x * 256 + threadIdx.x;           // 4*9*2*64 = 4608
    if (idx >= 4 * 9 * 2 * 64) return;
    int lane  = idx & 63;
    int mh    = (idx >> 6) & 1;
    int tap   = (idx >> 7) % 9;
    int layer = (idx >> 7) / 9;
    const float* w = layer == 0 ? w0 : layer == 1 ? w1 : layer == 2 ? w2 : w3;
    int cin_act = (layer == 0) ? 3 : 32;
    int cout = mh * 16 + (lane & 15);
    int cin0 = (lane >> 4) * 8;
    int dy = tap / 3, dx = tap % 3;
    u16 v[8];
    for (int j = 0; j < 8; j++) {
        int cin = cin0 + j;
        float f = (cin < cin_act) ? w[((cout * cin_act + cin) * 3 + dy) * 3 + dx] : 0.f;
        v[j] = f2bf(f);
    }
    uint4 pack;
    pack.x = (u32)v[0] | ((u32)v[1] << 16);
    pack.y = (u32)v[2] | ((u32)v[3] << 16);
    pack.z = (u32)v[4] | ((u32)v[5] << 16);
    pack.w = (u32)v[6] | ((u32)v[7] << 16);
    reinterpret_cast<uint4*>(wfrag)[idx] = pack;
}

// ------- FC weight prep: fp32 [10][32768 nchw] -> double-bf16 A-frags -------
__global__ void prep_wfc_k(const float* __restrict__ fcw, u16* __restrict__ wfc)
{
    int idx = blockIdx.x * 256 + threadIdx.x;           // 1024*64 = 65536
    int lane = idx & 63, step = idx >> 6;
    int j = lane & 15, kq = lane >> 4;
    u16 hi[8], lo[8];
#pragma unroll
    for (int e = 0; e < 8; e++) {
        int k = step * 32 + kq * 8 + e;                 // NHWC k
        int c = k & 31, p = k >> 5;
        float f = (j < 10) ? fcw[j * 32768 + c * 1024 + p] : 0.f;
        u16 h = f2bf(f);
        hi[e] = h;
        lo[e] = f2bf(f - bf2f(h));
    }
    uint4 ph, pl;
    ph.x = (u32)hi[0] | ((u32)hi[1] << 16); ph.y = (u32)hi[2] | ((u32)hi[3] << 16);
    ph.z = (u32)hi[4] | ((u32)hi[5] << 16); ph.w = (u32)hi[6] | ((u32)hi[7] << 16);
    pl.x = (u32)lo[0] | ((u32)lo[1] << 16); pl.y = (u32)lo[2] | ((u32)lo[3] << 16);
    pl.z = (u32)lo[4] | ((u32)lo[5] << 16); pl.w = (u32)lo[6] | ((u32)lo[7] << 16);
    reinterpret_cast<uint4*>(wfc)[idx] = ph;
    reinterpret_cast<uint4*>(wfc)[65536 + idx] = pl;
}

// ------------------------------ megakernel ----------------------------------
// block = 1 sample, 512 thr (8 waves). LDS ping-pong 2 x 1024pix x 32ch bf16,
// chunk-swizzled. wave w: output rows 4w..4w+3 (2 chunks of 2 rows, unrolled).
__global__ void __launch_bounds__(512, 1)
net_k(const float* __restrict__ x, const u16* __restrict__ wfrag,
      u16* __restrict__ u4, float* __restrict__ c4)
{
    __shared__ u16 lds[2][32768];
    __shared__ float red[8][4];                         // [wave][layer]
    __shared__ uint4 zslot;                             // zero B-frag for OOB
    const int b = blockIdx.x;
    const int tid = threadIdx.x;
    const int lane = tid & 63;
    const int wv = tid >> 6;
    const int px = lane & 15;
    const int kq = lane >> 4;
    float vn[4];

    // ---- cvt: fp32 NCHW -> bf16 NHWC(32ch, ch3..31=0), swizzled lds[0] ----
    const float* xb = x + (size_t)b * 3072;
    if (tid == 0) zslot = make_uint4(0, 0, 0, 0);
#pragma unroll
    for (int it = 0; it < 8; it++) {
        int pix = it * 128 + wv * 16 + px;              // wave covers 16 pix
        int c = kq;                                     // chunk = lane>>4
        uint4 val = make_uint4(0, 0, 0, 0);
        if (c == 0) {
            float f0 = xb[pix], f1 = xb[1024 + pix], f2 = xb[2048 + pix];
            val.x = (u32)bfc(f0) | ((u32)bfc(f1) << 16);
            val.y = (u32)bfc(f2);
        }
        *reinterpret_cast<uint4*>(&lds[0][swz(pix, c)]) = val;
    }

    const int orow0 = wv * 4;
#pragma unroll 1
    for (int l = 0; l < 4; l++) {
        bf16x8 W[3][3][2];
        const uint4* wl = reinterpret_cast<const uint4*>(wfrag + l * 9216);
#pragma unroll
        for (int dy = 0; dy < 3; dy++)
#pragma unroll
            for (int dx = 0; dx < 3; dx++)
#pragma unroll
                for (int mh = 0; mh < 2; mh++) {
                    frag_cast fc;
                    fc.u = wl[((dy * 3 + dx) * 2 + mh) * 64 + lane];
                    W[dy][dx][mh] = fc.f;
                }
        const u16* src = lds[l & 1];
        u16* dst = lds[(l & 1) ^ 1];
        f32x4 vacc = (f32x4)0.f;
        __syncthreads();                                // prev writes visible

#pragma unroll
        for (int ch = 0; ch < 2; ch++) {                // FULL unroll: CSE of
            const int oA = orow0 + ch * 2;              // shared-row reads
            f32x4 accA[2][2]; f32x4 accB[2][2];         // [mhalf][ntile]
#pragma unroll
            for (int mh = 0; mh < 2; mh++)
#pragma unroll
                for (int nt = 0; nt < 2; nt++) { accA[mh][nt] = (f32x4)0.f; accB[mh][nt] = (f32x4)0.f; }

#pragma unroll
            for (int k = 0; k < 4; k++) {
                int ri = oA - 1 + k;                    // input row
                if (ri >= 0 && ri < 32) {
                    bf16x8 bfr[2][3];                   // [ntile][dx]
#pragma unroll
                    for (int nt = 0; nt < 2; nt++)
#pragma unroll
                        for (int d = 0; d < 3; d++) {
                            int xx = nt * 16 + px + d - 1;
                            bool oob = ((unsigned)xx >= 32u);
                            int xs = oob ? (nt * 16 + px) : xx;
                            const uint4* pr = oob ? &zslot
                                : reinterpret_cast<const uint4*>(&src[swz(ri * 32 + xs, kq)]);
                            frag_cast fc;
                            fc.u = *pr;
                            bfr[nt][d] = fc.f;
                        }
                    if (k <= 2) {
#pragma unroll
                        for (int mh = 0; mh < 2; mh++)
#pragma unroll
                            for (int nt = 0; nt < 2; nt++)
#pragma unroll
                                for (int d = 0; d < 3; d++)
                                    accA[mh][nt] = __builtin_amdgcn_mfma_f32_16x16x32_bf16(
                                        W[k][d][mh], bfr[nt][d], accA[mh][nt], 0, 0, 0);
                    }
                    if (k >= 1) {
#pragma unroll
                        for (int mh = 0; mh < 2; mh++)
#pragma unroll
                            for (int nt = 0; nt < 2; nt++)
#pragma unroll
                                for (int d = 0; d < 3; d++)
                                    accB[mh][nt] = __builtin_amdgcn_mfma_f32_16x16x32_bf16(
                                        W[k - 1][d][mh], bfr[nt][d], accB[mh][nt], 0, 0, 0);
                    }
                }
            }
            // epilogue: D col=lane&15(px), row(ch)=(lane>>4)*4+r
#pragma unroll
            for (int mh = 0; mh < 2; mh++)
#pragma unroll
                for (int nt = 0; nt < 2; nt++) {
                    int cch = mh * 2 + (kq >> 1);
                    int sub = (kq & 1) * 4;
                    f32x4 a = accA[mh][nt];
                    vacc += a * a;
                    ushort4 h = make_ushort4(bfc(a[0]), bfc(a[1]), bfc(a[2]), bfc(a[3]));
                    int P0 = oA * 32 + nt * 16 + px;
                    *reinterpret_cast<ushort4*>(&dst[swz(P0, cch) + sub]) = h;
                    f32x4 c = accB[mh][nt];
                    vacc += c * c;
                    ushort4 h2 = make_ushort4(bfc(c[0]), bfc(c[1]), bfc(c[2]), bfc(c[3]));
                    int P1 = (oA + 1) * 32 + nt * 16 + px;
                    *reinterpret_cast<ushort4*>(&dst[swz(P1, cch) + sub]) = h2;
                }
        }
        vn[l] = vacc[0] + vacc[1] + vacc[2] + vacc[3];
    }

    // ---- norm chain -> c4[b] ----
#pragma unroll
    for (int l = 0; l < 4; l++)
#pragma unroll
        for (int off = 32; off; off >>= 1) vn[l] += __shfl_xor(vn[l], off);
    if (lane == 0) {
#pragma unroll
        for (int l = 0; l < 4; l++) red[wv][l] = vn[l];
    }
    __syncthreads();                                    // red + final lds[0] visible
    float c = 1.f;
#pragma unroll
    for (int l = 0; l < 4; l++) {
        float n = 0.f;
#pragma unroll
        for (int w = 0; w < 8; w++) n += red[w][l];
        c = c * (2.f / (2.f + c * c * n));
    }
    if (tid == 0) c4[b] = c;

    // ---- writeback final activation (lds[0], unswizzle -> linear NHWC) ----
    u16* ub = u4 + (size_t)b * 32768;
#pragma unroll
    for (int it = 0; it < 8; it++) {
        int pix = it * 128 + wv * 16 + px;
        int cch = kq;
        *reinterpret_cast<uint4*>(ub + pix * 32 + cch * 8) =
            *reinterpret_cast<const uint4*>(&lds[0][swz(pix, cch)]);
    }
}

// --------------- FC: MFMA, M=16(j), N=16 samples, 32-way k-split ------------
// Wave-private LDS staging: 4-lane-contiguous 64B global loads (coalesced),
// swizzled LDS slots (2-way banks), T14 split (load chunk c+1 -> regs, compute
// chunk c, then write regs -> LDS). No barriers (slots are wave-private).
#define FSTG 4
__global__ void __launch_bounds__(256)
fc_mfma_k(const u16* __restrict__ u4, const u16* __restrict__ wfc,
          float* __restrict__ tmp)
{
    __shared__ uint4 sb[2][4 * FSTG * 64];              // 2 x 16KB
    const int lane = threadIdx.x & 63;
    const int wv = threadIdx.x >> 6;
    // XCD-grouped remap: the 8 blocks sharing one sample-tile -> same bid&7
    const int rb = ((blockIdx.x & 7) << 6) + (blockIdx.x >> 3);
    const int wid = rb * 4 + wv;                        // 0..2047
    const int kc = wid & 31;                            // k-chunk (1024 elems)
    const int st = wid >> 5;                            // sample tile (16)
    const int px = lane & 15, kq = lane >> 4;
    const int a = lane >> 2, p = lane & 3;              // staging: sample, piece
    const u16* gB = u4 + (size_t)(st * 16 + a) * 32768 + kc * 1024 + p * 8;
    const int wslot = wv * FSTG * 64 + a * 4 + (p ^ (a & 3));
    const int rslot = wv * FSTG * 64 + px * 4 + (kq ^ (px & 3));
    const uint4* Ah = reinterpret_cast<const uint4*>(wfc) + kc * 32 * 64 + lane;
    const uint4* Al = Ah + 65536;
    f32x4 acc = (f32x4)0.f;
    uint4 rg[FSTG];

#pragma unroll
    for (int si = 0; si < FSTG; si++)
        rg[si] = *reinterpret_cast<const uint4*>(gB + si * 32);
#pragma unroll
    for (int si = 0; si < FSTG; si++)
        sb[0][wslot + si * 64] = rg[si];

#pragma unroll 1
    for (int c2 = 0; c2 < 8; c2++) {
        if (c2 < 7) {
#pragma unroll
            for (int si = 0; si < FSTG; si++)
                rg[si] = *reinterpret_cast<const uint4*>(gB + ((c2 + 1) * FSTG + si) * 32);
        }
#pragma unroll
        for (int si = 0; si < FSTG; si++) {
            int s = c2 * FSTG + si;
            frag_cast aa, al2, bb;
            aa.u  = Ah[s * 64];
            al2.u = Al[s * 64];
            bb.u  = sb[c2 & 1][rslot + si * 64];
            acc = __builtin_amdgcn_mfma_f32_16x16x32_bf16(aa.f,  bb.f, acc, 0, 0, 0);
            acc = __builtin_amdgcn_mfma_f32_16x16x32_bf16(al2.f, bb.f, acc, 0, 0, 0);
        }
        if (c2 < 7) {
#pragma unroll
            for (int si = 0; si < FSTG; si++)
                sb[(c2 + 1) & 1][wslot + si * 64] = rg[si];
        }
    }
    int sample = st * 16 + px;                          // D col = lane&15
#pragma unroll
    for (int r = 0; r < 4; r++) {
        int j = kq * 4 + r;                             // D row
        if (j < 10) atomicAdd(&tmp[sample * 10 + j], acc[r]);
    }
}

// ------------------- finalize: out = c4[b]*tmp + bias -----------------------
__global__ void finalize_k(const float* __restrict__ tmp, const float* __restrict__ c4,
                           const float* __restrict__ fcb, float* __restrict__ out)
{
    int i = blockIdx.x * 256 + threadIdx.x;
    if (i >= 10240) return;
    int b = i / 10, j = i - b * 10;
    out[i] = c4[b] * tmp[i] + fcb[j];
}

// ------------------------------- launcher -----------------------------------
extern "C" void kernel_launch(void* const* d_in, const int* in_sizes, int n_in,
                              void* d_out, int out_size, void* d_ws, size_t ws_size,
                              hipStream_t stream)
{
    const float* x   = (const float*)d_in[0];
    const float* cw0 = (const float*)d_in[1];
    const float* cw1 = (const float*)d_in[2];
    const float* cw2 = (const float*)d_in[3];
    const float* cw3 = (const float*)d_in[4];
    const float* fcw = (const float*)d_in[5];
    const float* fcb = (const float*)d_in[6];
    float* out = (float*)d_out;
    char* ws = (char*)d_ws;

    // ws layout (~66.2 MB)
    const size_t USZ = (size_t)1024 * 32768 * 2;        // 64 MB activations
    u16* uA    = (u16*)ws;
    u16* wfrag = (u16*)(ws + USZ);                      // 73728 B (pad 81920)
    u16* wfc   = (u16*)(ws + USZ + 81920);              // 2 MB (hi+lo)
    float* tmp = (float*)(ws + USZ + 81920 + 2097152);  // 40960 B
    float* c4  = tmp + 10240;                           // 4096 B

    hipMemsetAsync(tmp, 0, 10240 * sizeof(float), stream);
    prep_weights_k<<<18, 256, 0, stream>>>(cw0, cw1, cw2, cw3, wfrag);
    prep_wfc_k<<<256, 256, 0, stream>>>(fcw, wfc);
    net_k<<<1024, 512, 0, stream>>>(x, wfrag, uA, c4);
    fc_mfma_k<<<512, 256, 0, stream>>>(uA, wfc, tmp);
    finalize_k<<<40, 256, 0, stream>>>(tmp, c4, fcb, out);
}